// Round 18
// baseline (109.255 us; speedup 1.0000x reference)
//
#include <hip/hip_runtime.h>
#include <math.h>

#define T_DIM 2048
#define B_DIM 4
#define BT (B_DIM * T_DIM)
#define MODEL 512
#define OUTF 256
#define WSZ 16
#define WIN 33

#define BM 128
#define BN 64
#define BK 32

#define TB 16    // t-rows per attn block (2 rows per wave, 8 waves)
#define HALO 48  // staged window rows (TB + 32)
#define TS 72    // padded k-stride for EwT/Ab (144B = 16B-aligned)

// DIAGNOSTIC: x3 repeat on attn_gemmc only (idempotent; rep-boundary
// barrier). Surfaces its duration+counters above the ~42us poison fills.
// Remove next round.
#define REP_ATTN 3

// 2*log2(e): GEMM epilogues store E = 2^(ESCALE*z) so attn needs no exp.
#define ESCALE 2.885390081777927f
#define ECLAMP 30.0f

typedef __attribute__((ext_vector_type(8))) short bf16x8;
typedef __attribute__((ext_vector_type(4))) float f32x4;

__device__ inline unsigned short f2bf(float f) {
  unsigned int u = __float_as_uint(f);
  u += 0x7fffu + ((u >> 16) & 1u);  // RNE
  return (unsigned short)(u >> 16);
}
__device__ inline float bflo(unsigned int u) {
  return __uint_as_float(u << 16);
}
__device__ inline float bfhi(unsigned int u) {
  return __uint_as_float(u & 0xffff0000u);
}
__device__ inline float fast_sigmoid(float z) {
  return __builtin_amdgcn_rcpf(1.f + __expf(-z));
}

// ---- m97-style GEMM body: BM=128 x BN=64 x BK=32, 8 waves, dbuf LDS,
// 2-deep register prefetch; B staged directly from f32 W (transpose-scatter
// via 4 scalar ds_write_b16).
// MODE 0 (k rows [0,512)):  cb<4: x@Wh -> E-domain bf16 (+b_attn);
//                           cb>=4: x@Wl1 -> z1 f32 (+b_lin).
// MODE 1 (k rows [512,768)): cb<4: enc@We -> E-domain bf16;
//                            cb>=4: enc@Wl2 -> plain bf16.
template <int KS, int MODE>
__device__ __forceinline__ void gemm_body(
    unsigned short (*As)[BM * 40], unsigned short (*Bs)[BN * 40], int rb,
    const float* __restrict__ A, int lda,
    const float* __restrict__ W_attn, const float* __restrict__ W_lin,
    const float* __restrict__ b_attn, const float* __restrict__ b_lin,
    unsigned short* __restrict__ outb, float* __restrict__ outf,
    unsigned short* __restrict__ outb2) {
  const int tid = threadIdx.x;
  const int cb = rb >> 6, rp = rb & 63;  // bid%8 == rp%8 -> A panel per-XCD
  const int row0 = rp * BM;
  const int colg = (cb & 3) * 64;
  const float* Wsrc = (cb < 4) ? W_attn : W_lin;
  constexpr int wrow0 = (MODE == 0) ? 0 : 512;

  const int arow = tid >> 2, akp = (tid & 3) * 8;
  const int brow = tid >> 4, bcp = (tid & 15) * 4;
  const float* aptr = A + (size_t)(row0 + arow) * lda + akp;
  const float* bptr = Wsrc + (size_t)(wrow0 + brow) * OUTF + colg + bcp;

  float4 ra0[2], ra1[2], rbw[2];
  auto LOADS = [&](int sl, int ks) {
    const float* ap = aptr + ks * BK;
    ra0[sl] = *(const float4*)ap;
    ra1[sl] = *(const float4*)(ap + 4);
    rbw[sl] = *(const float4*)(bptr + (size_t)ks * BK * OUTF);
  };
  auto WRITE = [&](int sl, int buf) {
    unsigned short t[8] = {f2bf(ra0[sl].x), f2bf(ra0[sl].y), f2bf(ra0[sl].z),
                           f2bf(ra0[sl].w), f2bf(ra1[sl].x), f2bf(ra1[sl].y),
                           f2bf(ra1[sl].z), f2bf(ra1[sl].w)};
    *(uint4*)&As[buf][arow * 40 + akp] = *(const uint4*)t;
    Bs[buf][(bcp + 0) * 40 + brow] = f2bf(rbw[sl].x);
    Bs[buf][(bcp + 1) * 40 + brow] = f2bf(rbw[sl].y);
    Bs[buf][(bcp + 2) * 40 + brow] = f2bf(rbw[sl].z);
    Bs[buf][(bcp + 3) * 40 + brow] = f2bf(rbw[sl].w);
  };

  const int w = tid >> 6, lane = tid & 63;
  const int lr = lane & 15, kg = lane >> 4;
  const int rbase = (w & 3) * 32;
  const int cbase = (w >> 2) * 32;

  f32x4 acc[2][2] = {{{0.f, 0.f, 0.f, 0.f}, {0.f, 0.f, 0.f, 0.f}},
                     {{0.f, 0.f, 0.f, 0.f}, {0.f, 0.f, 0.f, 0.f}}};

  LOADS(0, 0);
  if (KS > 1) LOADS(1, 1);
  WRITE(0, 0);
  __syncthreads();

#pragma unroll
  for (int ks = 0; ks < KS; ++ks) {
    if (ks + 2 < KS) LOADS(ks & 1, ks + 2);
    const int bf = ks & 1;
    bf16x8 a0 = *(const bf16x8*)&As[bf][(rbase + lr) * 40 + kg * 8];
    bf16x8 a1 = *(const bf16x8*)&As[bf][(rbase + 16 + lr) * 40 + kg * 8];
    bf16x8 b0 = *(const bf16x8*)&Bs[bf][(cbase + lr) * 40 + kg * 8];
    bf16x8 b1 = *(const bf16x8*)&Bs[bf][(cbase + 16 + lr) * 40 + kg * 8];
    acc[0][0] = __builtin_amdgcn_mfma_f32_16x16x32_bf16(a0, b0, acc[0][0], 0, 0, 0);
    acc[0][1] = __builtin_amdgcn_mfma_f32_16x16x32_bf16(a0, b1, acc[0][1], 0, 0, 0);
    acc[1][0] = __builtin_amdgcn_mfma_f32_16x16x32_bf16(a1, b0, acc[1][0], 0, 0, 0);
    acc[1][1] = __builtin_amdgcn_mfma_f32_16x16x32_bf16(a1, b1, acc[1][1], 0, 0, 0);
    if (ks + 1 < KS) WRITE((ks + 1) & 1, (ks + 1) & 1);
    __syncthreads();
  }

  // C/D layout: col=lane&15, row=(lane>>4)*4+r  [m89-verified]
#pragma unroll
  for (int m = 0; m < 2; ++m) {
#pragma unroll
    for (int f = 0; f < 2; ++f) {
      const int col = colg + cbase + f * 16 + lr;
#pragma unroll
      for (int r = 0; r < 4; ++r) {
        const int row = row0 + rbase + m * 16 + kg * 4 + r;
        float val = acc[m][f][r];
        if (MODE == 0) {
          if (cb < 4) {
            const float y = fminf((val + b_attn[col]) * ESCALE, ECLAMP);
            outb[(size_t)row * OUTF + col] = f2bf(__builtin_amdgcn_exp2f(y));
          } else {
            outf[(size_t)row * OUTF + col] = val + b_lin[col];
          }
        } else {
          if (cb < 4) {
            const float y = fminf(val * ESCALE, ECLAMP);
            outb[(size_t)row * OUTF + col] = f2bf(__builtin_amdgcn_exp2f(y));
          } else {
            outb2[(size_t)row * OUTF + col] = f2bf(val);
          }
        }
      }
    }
  }
}

// [0,512): x@[Wh|Wl1] -> xwe2,z1 ; [512,1024): enc@We -> ewe2, enc@Wl2 -> encWl2
__global__ __launch_bounds__(512) void gemmAB_kernel(
    const float* __restrict__ x, const float* __restrict__ enc,
    const float* __restrict__ W_attn, const float* __restrict__ W_lin,
    const float* __restrict__ b_attn, const float* __restrict__ b_lin,
    unsigned short* __restrict__ xwe2, float* __restrict__ z1,
    unsigned short* __restrict__ ewe2, unsigned short* __restrict__ encWl2) {
  __shared__ unsigned short As[2][BM * 40];
  __shared__ unsigned short Bs[2][BN * 40];
  if (blockIdx.x < 512)
    gemm_body<16, 0>(As, Bs, blockIdx.x, x, MODEL, W_attn, W_lin, b_attn,
                     b_lin, xwe2, z1, nullptr);
  else
    gemm_body<8, 1>(As, Bs, blockIdx.x - 512, enc, OUTF, W_attn, W_lin,
                    nullptr, nullptr, ewe2, nullptr, encWl2);
}

// ---- fused attention + banded final GEMM: 16 t-rows/block, 2 rows/wave ----
// x3 DIAGNOSTIC REPEAT this round (idempotent).
__global__ __launch_bounds__(512) void attn_gemmc_kernel(
    const unsigned short* __restrict__ xwe2,
    const unsigned short* __restrict__ ewe2,
    const unsigned short* __restrict__ encWl2, const float* __restrict__ v,
    const float* __restrict__ z1, float* __restrict__ out,
    float* __restrict__ a_out) {
  __shared__ unsigned short Ew[HALO * 256];  // 2^encwe halo (24.6 KB)
  __shared__ unsigned short EwT[256 * TS];   // (encWl2 halo)^T (36.9 KB)
  __shared__ unsigned short Ab[TB * TS];     // banded a (2.3 KB)

  const int tid = threadIdx.x;
  const int wv = tid >> 6, lane = tid & 63;
  const int rb = ((blockIdx.x & 7) << 6) | (blockIdx.x >> 3);  // XCD-grouped
  const int t0 = rb * TB;
  const int b = t0 >> 11;
  const int tloc = t0 & (T_DIM - 1);
  const int g = lane >> 4, sl = lane & 15;

  // zero Ab and EwT k-slice [48,64) (0*garbage = NaN otherwise)
  if (tid < TB * TS / 8) ((uint4*)Ab)[tid] = make_uint4(0, 0, 0, 0);
  {
    const int col = tid >> 1, off = 48 + (tid & 1) * 8;
    *(uint4*)&EwT[col * TS + off] = make_uint4(0, 0, 0, 0);
  }

  float vf[16];
  {
    const float4* vp = (const float4*)(v + sl * 16);
#pragma unroll
    for (int j = 0; j < 4; ++j) {
      float4 t4 = vp[j];
      vf[4 * j] = t4.x; vf[4 * j + 1] = t4.y;
      vf[4 * j + 2] = t4.z; vf[4 * j + 3] = t4.w;
    }
  }

  for (int rep = 0; rep < REP_ATTN; ++rep) {  // diagnostic repeat
    __syncthreads();  // prior rep's LDS reads all done before restaging

    // stage Ew (2^ewe, OOB rows = 1.0) and EwT (encWl2 transposed, OOB = 0)
    for (int u = tid; u < HALO * 32; u += 512) {
      const int r = u >> 5, s = u & 31;
      const int tg = tloc - WSZ + r;
      uint4 qe, qw;
      if ((unsigned)tg < T_DIM) {
        const size_t base = ((size_t)(b * T_DIM + tg)) << 8;
        qe = *(const uint4*)(ewe2 + base + s * 8);
        qw = *(const uint4*)(encWl2 + base + s * 8);
      } else {
        qe = make_uint4(0x3f803f80u, 0x3f803f80u, 0x3f803f80u, 0x3f803f80u);
        qw = make_uint4(0, 0, 0, 0);
      }
      *(uint4*)&Ew[r * 256 + s * 8] = qe;
      unsigned short tt[8];
      *(uint4*)tt = qw;
#pragma unroll
      for (int j = 0; j < 8; ++j) EwT[(s * 8 + j) * TS + r] = tt[j];
    }
    __syncthreads();

    const int lrow = wv * 2;
    const int bt0 = t0 + lrow, bt1 = bt0 + 1;

    float xe0[16], xe1[16];
    {
      const uint4* xp0 = (const uint4*)(xwe2 + ((size_t)bt0 << 8) + sl * 16);
      const uint4* xp1 = (const uint4*)(xwe2 + ((size_t)bt1 << 8) + sl * 16);
      uint4 q0 = xp0[0], q1 = xp0[1], q2 = xp1[0], q3 = xp1[1];
      unsigned int u0[8] = {q0.x, q0.y, q0.z, q0.w, q1.x, q1.y, q1.z, q1.w};
      unsigned int u1[8] = {q2.x, q2.y, q2.z, q2.w, q3.x, q3.y, q3.z, q3.w};
#pragma unroll
      for (int j = 0; j < 8; ++j) {
        xe0[2 * j] = bflo(u0[j]); xe0[2 * j + 1] = bfhi(u0[j]);
        xe1[2 * j] = bflo(u1[j]); xe1[2 * j + 1] = bfhi(u1[j]);
      }
    }

    // scores for BOTH rows: 9 chunks x 4 windows (16 lanes each)
    float s0 = 0.f, s1 = 0.f;
#pragma unroll
    for (int c = 0; c < 9; ++c) {
      const int w_ = c * 4 + g;
      const int rl0 = min(lrow + w_, HALO - 1);
      const int rl1 = min(lrow + 1 + w_, HALO - 1);
      const uint4 a0q = *(const uint4*)&Ew[rl0 * 256 + sl * 16];
      const uint4 a1q = *(const uint4*)&Ew[rl0 * 256 + sl * 16 + 8];
      const uint4 b0q = *(const uint4*)&Ew[rl1 * 256 + sl * 16];
      const uint4 b1q = *(const uint4*)&Ew[rl1 * 256 + sl * 16 + 8];
      unsigned int e0[8] = {a0q.x, a0q.y, a0q.z, a0q.w, a1q.x, a1q.y, a1q.z, a1q.w};
      unsigned int e1[8] = {b0q.x, b0q.y, b0q.z, b0q.w, b1q.x, b1q.y, b1q.z, b1q.w};
      float acc0 = 0.f, acc1 = 0.f;
#pragma unroll
      for (int j = 0; j < 8; ++j) {
        const float v0 = vf[2 * j], v1 = vf[2 * j + 1];
        const float vsj = v0 + v1;
        {
          const float E0 = xe0[2 * j] * bflo(e0[j]);
          const float E1 = xe0[2 * j + 1] * bfhi(e0[j]);
          const float den = (E0 + 1.f) * (E1 + 1.f);
          float num = fmaf(v0, E1, vsj);
          num = fmaf(v1, E0, num);
          acc0 = fmaf(num, __builtin_amdgcn_rcpf(den), acc0);
        }
        {
          const float E0 = xe1[2 * j] * bflo(e1[j]);
          const float E1 = xe1[2 * j + 1] * bfhi(e1[j]);
          const float den = (E0 + 1.f) * (E1 + 1.f);
          float num = fmaf(v0, E1, vsj);
          num = fmaf(v1, E0, num);
          acc1 = fmaf(num, __builtin_amdgcn_rcpf(den), acc1);
        }
      }
#pragma unroll
      for (int off = 1; off < 16; off <<= 1) {
        acc0 += __shfl_xor(acc0, off);
        acc1 += __shfl_xor(acc1, off);
      }
      const int src = (lane & 3) << 4;
      float c0v = __shfl(acc0, src), c1v = __shfl(acc1, src);
      if ((lane >> 2) == c) { s0 = c0v; s1 = c1v; }
    }

    // softmax without max-subtraction: score=-2S, |S|<=sum|v|~4.2 -> safe
    float p0 = (lane < WIN) ? __builtin_amdgcn_exp2f(-ESCALE * s0) : 0.f;
    float p1 = (lane < WIN) ? __builtin_amdgcn_exp2f(-ESCALE * s1) : 0.f;
    float q0 = p0, q1 = p1;
#pragma unroll
    for (int off = 1; off < 64; off <<= 1) {
      q0 += __shfl_xor(q0, off);
      q1 += __shfl_xor(q1, off);
    }
    const float a0v = p0 * __builtin_amdgcn_rcpf(q0);
    const float a1v = p1 * __builtin_amdgcn_rcpf(q1);
    if (lane < WIN) {
      a_out[(size_t)bt0 * WIN + lane] = a0v;
      a_out[(size_t)bt1 * WIN + lane] = a1v;
      Ab[lrow * TS + lrow + lane] = f2bf(a0v);
      Ab[(lrow + 1) * TS + (lrow + 1) + lane] = f2bf(a1v);
    }
    __syncthreads();

    // banded GEMM: out[16,256] = sigmoid(z1 + Ab(16x64) @ EwT^T(64x256))
    const int lr = lane & 15, kg = lane >> 4;
    f32x4 acc[2] = {{0.f, 0.f, 0.f, 0.f}, {0.f, 0.f, 0.f, 0.f}};
#pragma unroll
    for (int ks = 0; ks < 2; ++ks) {
      bf16x8 a = *(const bf16x8*)&Ab[lr * TS + ks * 32 + kg * 8];
#pragma unroll
      for (int f = 0; f < 2; ++f) {
        bf16x8 bb = *(const bf16x8*)&EwT[(wv * 32 + f * 16 + lr) * TS +
                                         ks * 32 + kg * 8];
        acc[f] = __builtin_amdgcn_mfma_f32_16x16x32_bf16(a, bb, acc[f], 0, 0, 0);
      }
    }
#pragma unroll
    for (int f = 0; f < 2; ++f) {
      const int col = wv * 32 + f * 16 + lr;
#pragma unroll
      for (int r = 0; r < 4; ++r) {
        const int row = t0 + kg * 4 + r;
        out[(size_t)row * OUTF + col] =
            fast_sigmoid(acc[f][r] + z1[(size_t)row * OUTF + col]);
      }
    }
  }
}

extern "C" void kernel_launch(void* const* d_in, const int* in_sizes, int n_in,
                              void* d_out, int out_size, void* d_ws,
                              size_t ws_size, hipStream_t stream) {
  const float* x      = (const float*)d_in[0];  // [4,2048,512]
  const float* enc    = (const float*)d_in[1];  // [4,2048,256]
  const float* W_attn = (const float*)d_in[2];  // [768,256]
  const float* b_attn = (const float*)d_in[3];  // [256]
  const float* v      = (const float*)d_in[4];  // [256]
  const float* W_lin  = (const float*)d_in[5];  // [768,256]
  const float* b_lin  = (const float*)d_in[6];  // [256]

  float* out   = (float*)d_out;            // [BT,256]
  float* a_out = out + (size_t)BT * OUTF;  // [BT,33]

  unsigned short* xwe2   = (unsigned short*)d_ws;     // BT*256 bf16 (2^ vals)
  unsigned short* ewe2   = xwe2 + (size_t)BT * OUTF;  // BT*256 bf16 (2^ vals)
  unsigned short* encWl2 = ewe2 + (size_t)BT * OUTF;  // BT*256 bf16
  float*          z1     = (float*)(encWl2 + (size_t)BT * OUTF);  // BT*256 f32

  // x@[Wh|Wl1] -> xwe2,z1 ; enc@We -> ewe2 ; enc@Wl2 -> encWl2
  gemmAB_kernel<<<1024, 512, 0, stream>>>(x, enc, W_attn, W_lin, b_attn,
                                          b_lin, xwe2, z1, ewe2, encWl2);
  // fused attention + banded final GEMM (+sigmoid) -> out, a_out  [x3 diag]
  attn_gemmc_kernel<<<512, 512, 0, stream>>>(xwe2, ewe2, encWl2, v, z1,
                                             out, a_out);
}

// Round 19
// 47.885 us; speedup vs baseline: 2.2816x; 2.2816x over previous
//
#include <hip/hip_runtime.h>
#include <math.h>

#define T_DIM 2048
#define B_DIM 4
#define BT (B_DIM * T_DIM)
#define MODEL 512
#define OUTF 256
#define WSZ 16
#define WIN 33

#define BM 128
#define BN 64
#define BK 32

#define TB 16    // t-rows per attn block (2 rows per wave, 8 waves)
#define HALO 48  // staged window rows (TB + 32)
#define TS 72    // padded k-stride for EwT/Ab (144B = 16B-aligned)

// 2*log2(e): GEMM epilogues store E = 2^(ESCALE*z) so attn needs no exp.
#define ESCALE 2.885390081777927f
#define ECLAMP 30.0f

typedef __attribute__((ext_vector_type(8))) short bf16x8;
typedef __attribute__((ext_vector_type(4))) float f32x4;

__device__ inline unsigned short f2bf(float f) {
  unsigned int u = __float_as_uint(f);
  u += 0x7fffu + ((u >> 16) & 1u);  // RNE
  return (unsigned short)(u >> 16);
}
__device__ inline float bflo(unsigned int u) {
  return __uint_as_float(u << 16);
}
__device__ inline float bfhi(unsigned int u) {
  return __uint_as_float(u & 0xffff0000u);
}
__device__ inline float fast_sigmoid(float z) {
  return __builtin_amdgcn_rcpf(1.f + __expf(-z));
}

// ---- m97-style GEMM body: BM=128 x BN=64 x BK=32, 8 waves, dbuf LDS,
// 2-deep register prefetch; B staged directly from f32 W (transpose-scatter
// via 4 scalar ds_write_b16).
// MODE 0 (k rows [0,512)):  cb<4: x@Wh -> E-domain bf16 (+b_attn);
//                           cb>=4: x@Wl1 -> z1 f32 (+b_lin).
// MODE 1 (k rows [512,768)): cb<4: enc@We -> E-domain bf16;
//                            cb>=4: enc@Wl2 -> plain bf16.
template <int KS, int MODE>
__device__ __forceinline__ void gemm_body(
    unsigned short (*As)[BM * 40], unsigned short (*Bs)[BN * 40], int rb,
    const float* __restrict__ A, int lda,
    const float* __restrict__ W_attn, const float* __restrict__ W_lin,
    const float* __restrict__ b_attn, const float* __restrict__ b_lin,
    unsigned short* __restrict__ outb, float* __restrict__ outf,
    unsigned short* __restrict__ outb2) {
  const int tid = threadIdx.x;
  const int cb = rb >> 6, rp = rb & 63;  // bid%8 == rp%8 -> A panel per-XCD
  const int row0 = rp * BM;
  const int colg = (cb & 3) * 64;
  const float* Wsrc = (cb < 4) ? W_attn : W_lin;
  constexpr int wrow0 = (MODE == 0) ? 0 : 512;

  const int arow = tid >> 2, akp = (tid & 3) * 8;
  const int brow = tid >> 4, bcp = (tid & 15) * 4;
  const float* aptr = A + (size_t)(row0 + arow) * lda + akp;
  const float* bptr = Wsrc + (size_t)(wrow0 + brow) * OUTF + colg + bcp;

  float4 ra0[2], ra1[2], rbw[2];
  auto LOADS = [&](int sl, int ks) {
    const float* ap = aptr + ks * BK;
    ra0[sl] = *(const float4*)ap;
    ra1[sl] = *(const float4*)(ap + 4);
    rbw[sl] = *(const float4*)(bptr + (size_t)ks * BK * OUTF);
  };
  auto WRITE = [&](int sl, int buf) {
    unsigned short t[8] = {f2bf(ra0[sl].x), f2bf(ra0[sl].y), f2bf(ra0[sl].z),
                           f2bf(ra0[sl].w), f2bf(ra1[sl].x), f2bf(ra1[sl].y),
                           f2bf(ra1[sl].z), f2bf(ra1[sl].w)};
    *(uint4*)&As[buf][arow * 40 + akp] = *(const uint4*)t;
    Bs[buf][(bcp + 0) * 40 + brow] = f2bf(rbw[sl].x);
    Bs[buf][(bcp + 1) * 40 + brow] = f2bf(rbw[sl].y);
    Bs[buf][(bcp + 2) * 40 + brow] = f2bf(rbw[sl].z);
    Bs[buf][(bcp + 3) * 40 + brow] = f2bf(rbw[sl].w);
  };

  const int w = tid >> 6, lane = tid & 63;
  const int lr = lane & 15, kg = lane >> 4;
  const int rbase = (w & 3) * 32;
  const int cbase = (w >> 2) * 32;

  f32x4 acc[2][2] = {{{0.f, 0.f, 0.f, 0.f}, {0.f, 0.f, 0.f, 0.f}},
                     {{0.f, 0.f, 0.f, 0.f}, {0.f, 0.f, 0.f, 0.f}}};

  LOADS(0, 0);
  if (KS > 1) LOADS(1, 1);
  WRITE(0, 0);
  __syncthreads();

#pragma unroll
  for (int ks = 0; ks < KS; ++ks) {
    if (ks + 2 < KS) LOADS(ks & 1, ks + 2);
    const int bf = ks & 1;
    bf16x8 a0 = *(const bf16x8*)&As[bf][(rbase + lr) * 40 + kg * 8];
    bf16x8 a1 = *(const bf16x8*)&As[bf][(rbase + 16 + lr) * 40 + kg * 8];
    bf16x8 b0 = *(const bf16x8*)&Bs[bf][(cbase + lr) * 40 + kg * 8];
    bf16x8 b1 = *(const bf16x8*)&Bs[bf][(cbase + 16 + lr) * 40 + kg * 8];
    acc[0][0] = __builtin_amdgcn_mfma_f32_16x16x32_bf16(a0, b0, acc[0][0], 0, 0, 0);
    acc[0][1] = __builtin_amdgcn_mfma_f32_16x16x32_bf16(a0, b1, acc[0][1], 0, 0, 0);
    acc[1][0] = __builtin_amdgcn_mfma_f32_16x16x32_bf16(a1, b0, acc[1][0], 0, 0, 0);
    acc[1][1] = __builtin_amdgcn_mfma_f32_16x16x32_bf16(a1, b1, acc[1][1], 0, 0, 0);
    if (ks + 1 < KS) WRITE((ks + 1) & 1, (ks + 1) & 1);
    __syncthreads();
  }

  // C/D layout: col=lane&15, row=(lane>>4)*4+r  [m89-verified]
#pragma unroll
  for (int m = 0; m < 2; ++m) {
#pragma unroll
    for (int f = 0; f < 2; ++f) {
      const int col = colg + cbase + f * 16 + lr;
#pragma unroll
      for (int r = 0; r < 4; ++r) {
        const int row = row0 + rbase + m * 16 + kg * 4 + r;
        float val = acc[m][f][r];
        if (MODE == 0) {
          if (cb < 4) {
            const float y = fminf((val + b_attn[col]) * ESCALE, ECLAMP);
            outb[(size_t)row * OUTF + col] = f2bf(__builtin_amdgcn_exp2f(y));
          } else {
            outf[(size_t)row * OUTF + col] = val + b_lin[col];
          }
        } else {
          if (cb < 4) {
            const float y = fminf(val * ESCALE, ECLAMP);
            outb[(size_t)row * OUTF + col] = f2bf(__builtin_amdgcn_exp2f(y));
          } else {
            outb2[(size_t)row * OUTF + col] = f2bf(val);
          }
        }
      }
    }
  }
}

// [0,512): x@[Wh|Wl1] -> xwe2,z1 ; [512,1024): enc@We -> ewe2, enc@Wl2 -> encWl2
__global__ __launch_bounds__(512) void gemmAB_kernel(
    const float* __restrict__ x, const float* __restrict__ enc,
    const float* __restrict__ W_attn, const float* __restrict__ W_lin,
    const float* __restrict__ b_attn, const float* __restrict__ b_lin,
    unsigned short* __restrict__ xwe2, float* __restrict__ z1,
    unsigned short* __restrict__ ewe2, unsigned short* __restrict__ encWl2) {
  __shared__ unsigned short As[2][BM * 40];
  __shared__ unsigned short Bs[2][BN * 40];
  if (blockIdx.x < 512)
    gemm_body<16, 0>(As, Bs, blockIdx.x, x, MODEL, W_attn, W_lin, b_attn,
                     b_lin, xwe2, z1, nullptr);
  else
    gemm_body<8, 1>(As, Bs, blockIdx.x - 512, enc, OUTF, W_attn, W_lin,
                    nullptr, nullptr, ewe2, nullptr, encWl2);
}

// ---- fused attention + banded final GEMM: 16 t-rows/block, 2 rows/wave ----
// R18: G4 XOR swizzles kill the bank conflicts found by the R17 diagnostic
// (6.9M/rep, mostly the EwT transpose-scatter's 32-way pattern):
//   Ew : idx ^ ((row&7)<<3) on write and read (16-way -> ~4-way reads)
//   EwT: k-granule ^ (((col>>3)&7)<<3) on scatter-write, zero-fill and
//        MFMA read (32-way scatter -> 4-way; reads stay <=2-way)
__global__ __launch_bounds__(512) void attn_gemmc_kernel(
    const unsigned short* __restrict__ xwe2,
    const unsigned short* __restrict__ ewe2,
    const unsigned short* __restrict__ encWl2, const float* __restrict__ v,
    const float* __restrict__ z1, float* __restrict__ out,
    float* __restrict__ a_out) {
  __shared__ unsigned short Ew[HALO * 256];  // 2^encwe halo (24.6 KB)
  __shared__ unsigned short EwT[256 * TS];   // (encWl2 halo)^T (36.9 KB)
  __shared__ unsigned short Ab[TB * TS];     // banded a (2.3 KB)

  const int tid = threadIdx.x;
  const int wv = tid >> 6, lane = tid & 63;
  const int rb = ((blockIdx.x & 7) << 6) | (blockIdx.x >> 3);  // XCD-grouped
  const int t0 = rb * TB;
  const int b = t0 >> 11;
  const int tloc = t0 & (T_DIM - 1);
  const int g = lane >> 4, sl = lane & 15;

  // zero Ab (cols >=48 must be 0 for the K=64 MFMA)
  if (tid < TB * TS / 8) ((uint4*)Ab)[tid] = make_uint4(0, 0, 0, 0);
  // zero EwT k-granules that staging doesn't cover (swizzled positions)
  {
    const int col = tid >> 1, off = 48 + (tid & 1) * 8;
    const int kswz = ((col >> 3) & 7) << 3;
    *(uint4*)&EwT[col * TS + (off ^ kswz)] = make_uint4(0, 0, 0, 0);
  }

  // stage Ew (2^ewe, OOB rows = 1.0) and EwT (encWl2 transposed, OOB = 0)
  for (int u = tid; u < HALO * 32; u += 512) {
    const int r = u >> 5, s = u & 31;
    const int tg = tloc - WSZ + r;
    uint4 qe, qw;
    if ((unsigned)tg < T_DIM) {
      const size_t base = ((size_t)(b * T_DIM + tg)) << 8;
      qe = *(const uint4*)(ewe2 + base + s * 8);
      qw = *(const uint4*)(encWl2 + base + s * 8);
    } else {
      qe = make_uint4(0x3f803f80u, 0x3f803f80u, 0x3f803f80u, 0x3f803f80u);
      qw = make_uint4(0, 0, 0, 0);
    }
    *(uint4*)&Ew[(r * 256 + s * 8) ^ ((r & 7) << 3)] = qe;
    unsigned short tt[8];
    *(uint4*)tt = qw;
    const int rsw = r ^ ((s & 7) << 3);  // key = col>>3 = s
#pragma unroll
    for (int j = 0; j < 8; ++j) EwT[(s * 8 + j) * TS + rsw] = tt[j];
  }

  float vf[16];
  {
    const float4* vp = (const float4*)(v + sl * 16);
#pragma unroll
    for (int j = 0; j < 4; ++j) {
      float4 t4 = vp[j];
      vf[4 * j] = t4.x; vf[4 * j + 1] = t4.y;
      vf[4 * j + 2] = t4.z; vf[4 * j + 3] = t4.w;
    }
  }
  __syncthreads();

  const int lrow = wv * 2;
  const int bt0 = t0 + lrow, bt1 = bt0 + 1;

  float xe0[16], xe1[16];
  {
    const uint4* xp0 = (const uint4*)(xwe2 + ((size_t)bt0 << 8) + sl * 16);
    const uint4* xp1 = (const uint4*)(xwe2 + ((size_t)bt1 << 8) + sl * 16);
    uint4 q0 = xp0[0], q1 = xp0[1], q2 = xp1[0], q3 = xp1[1];
    unsigned int u0[8] = {q0.x, q0.y, q0.z, q0.w, q1.x, q1.y, q1.z, q1.w};
    unsigned int u1[8] = {q2.x, q2.y, q2.z, q2.w, q3.x, q3.y, q3.z, q3.w};
#pragma unroll
    for (int j = 0; j < 8; ++j) {
      xe0[2 * j] = bflo(u0[j]); xe0[2 * j + 1] = bfhi(u0[j]);
      xe1[2 * j] = bflo(u1[j]); xe1[2 * j + 1] = bfhi(u1[j]);
    }
  }

  // scores for BOTH rows: 9 chunks x 4 windows (16 lanes each)
  float s0 = 0.f, s1 = 0.f;
#pragma unroll
  for (int c = 0; c < 9; ++c) {
    const int w_ = c * 4 + g;
    const int rl0 = min(lrow + w_, HALO - 1);
    const int rl1 = min(lrow + 1 + w_, HALO - 1);
    const int x0 = (rl0 & 7) << 3, x1 = (rl1 & 7) << 3;
    const int b0i = rl0 * 256 + sl * 16, b1i = rl1 * 256 + sl * 16;
    const uint4 a0q = *(const uint4*)&Ew[b0i ^ x0];
    const uint4 a1q = *(const uint4*)&Ew[(b0i + 8) ^ x0];
    const uint4 b0q = *(const uint4*)&Ew[b1i ^ x1];
    const uint4 b1q = *(const uint4*)&Ew[(b1i + 8) ^ x1];
    unsigned int e0[8] = {a0q.x, a0q.y, a0q.z, a0q.w, a1q.x, a1q.y, a1q.z, a1q.w};
    unsigned int e1[8] = {b0q.x, b0q.y, b0q.z, b0q.w, b1q.x, b1q.y, b1q.z, b1q.w};
    float acc0 = 0.f, acc1 = 0.f;
#pragma unroll
    for (int j = 0; j < 8; ++j) {
      const float v0 = vf[2 * j], v1 = vf[2 * j + 1];
      const float vsj = v0 + v1;
      {
        const float E0 = xe0[2 * j] * bflo(e0[j]);
        const float E1 = xe0[2 * j + 1] * bfhi(e0[j]);
        const float den = (E0 + 1.f) * (E1 + 1.f);
        float num = fmaf(v0, E1, vsj);
        num = fmaf(v1, E0, num);
        acc0 = fmaf(num, __builtin_amdgcn_rcpf(den), acc0);
      }
      {
        const float E0 = xe1[2 * j] * bflo(e1[j]);
        const float E1 = xe1[2 * j + 1] * bfhi(e1[j]);
        const float den = (E0 + 1.f) * (E1 + 1.f);
        float num = fmaf(v0, E1, vsj);
        num = fmaf(v1, E0, num);
        acc1 = fmaf(num, __builtin_amdgcn_rcpf(den), acc1);
      }
    }
#pragma unroll
    for (int off = 1; off < 16; off <<= 1) {
      acc0 += __shfl_xor(acc0, off);
      acc1 += __shfl_xor(acc1, off);
    }
    const int src = (lane & 3) << 4;
    float c0v = __shfl(acc0, src), c1v = __shfl(acc1, src);
    if ((lane >> 2) == c) { s0 = c0v; s1 = c1v; }
  }

  // softmax without max-subtraction: score=-2S, |S|<=sum|v|~4.2 -> safe
  float p0 = (lane < WIN) ? __builtin_amdgcn_exp2f(-ESCALE * s0) : 0.f;
  float p1 = (lane < WIN) ? __builtin_amdgcn_exp2f(-ESCALE * s1) : 0.f;
  float q0 = p0, q1 = p1;
#pragma unroll
  for (int off = 1; off < 64; off <<= 1) {
    q0 += __shfl_xor(q0, off);
    q1 += __shfl_xor(q1, off);
  }
  const float a0v = p0 * __builtin_amdgcn_rcpf(q0);
  const float a1v = p1 * __builtin_amdgcn_rcpf(q1);
  if (lane < WIN) {
    a_out[(size_t)bt0 * WIN + lane] = a0v;
    a_out[(size_t)bt1 * WIN + lane] = a1v;
    // banded a-matrix: Ab[t][t+w] = a[t][w]; rest stays 0.
    Ab[lrow * TS + lrow + lane] = f2bf(a0v);
    Ab[(lrow + 1) * TS + (lrow + 1) + lane] = f2bf(a1v);
  }
  __syncthreads();

  // banded GEMM: out[16,256] = sigmoid(z1 + Ab(16x64) @ EwT^T(64x256))
  const int lr = lane & 15, kg = lane >> 4;
  f32x4 acc[2] = {{0.f, 0.f, 0.f, 0.f}, {0.f, 0.f, 0.f, 0.f}};
#pragma unroll
  for (int ks = 0; ks < 2; ++ks) {
    bf16x8 a = *(const bf16x8*)&Ab[lr * TS + ks * 32 + kg * 8];
#pragma unroll
    for (int f = 0; f < 2; ++f) {
      const int colB = wv * 32 + f * 16 + lr;
      const int kswz = ((colB >> 3) & 7) << 3;
      bf16x8 bb = *(const bf16x8*)&EwT[colB * TS + ((ks * 32 + kg * 8) ^ kswz)];
      acc[f] = __builtin_amdgcn_mfma_f32_16x16x32_bf16(a, bb, acc[f], 0, 0, 0);
    }
  }
#pragma unroll
  for (int f = 0; f < 2; ++f) {
    const int col = wv * 32 + f * 16 + lr;
#pragma unroll
    for (int r = 0; r < 4; ++r) {
      const int row = t0 + kg * 4 + r;
      out[(size_t)row * OUTF + col] =
          fast_sigmoid(acc[f][r] + z1[(size_t)row * OUTF + col]);
    }
  }
}

extern "C" void kernel_launch(void* const* d_in, const int* in_sizes, int n_in,
                              void* d_out, int out_size, void* d_ws,
                              size_t ws_size, hipStream_t stream) {
  const float* x      = (const float*)d_in[0];  // [4,2048,512]
  const float* enc    = (const float*)d_in[1];  // [4,2048,256]
  const float* W_attn = (const float*)d_in[2];  // [768,256]
  const float* b_attn = (const float*)d_in[3];  // [256]
  const float* v      = (const float*)d_in[4];  // [256]
  const float* W_lin  = (const float*)d_in[5];  // [768,256]
  const float* b_lin  = (const float*)d_in[6];  // [256]

  float* out   = (float*)d_out;            // [BT,256]
  float* a_out = out + (size_t)BT * OUTF;  // [BT,33]

  unsigned short* xwe2   = (unsigned short*)d_ws;     // BT*256 bf16 (2^ vals)
  unsigned short* ewe2   = xwe2 + (size_t)BT * OUTF;  // BT*256 bf16 (2^ vals)
  unsigned short* encWl2 = ewe2 + (size_t)BT * OUTF;  // BT*256 bf16
  float*          z1     = (float*)(encWl2 + (size_t)BT * OUTF);  // BT*256 f32

  // x@[Wh|Wl1] -> xwe2,z1 ; enc@We -> ewe2 ; enc@Wl2 -> encWl2
  gemmAB_kernel<<<1024, 512, 0, stream>>>(x, enc, W_attn, W_lin, b_attn,
                                          b_lin, xwe2, z1, ewe2, encWl2);
  // fused attention + banded final GEMM (+sigmoid) -> out, a_out
  attn_gemmc_kernel<<<512, 512, 0, stream>>>(xwe2, ewe2, encWl2, v, z1,
                                             out, a_out);
}

// Round 20
// 42.757 us; speedup vs baseline: 2.5553x; 1.1199x over previous
//
#include <hip/hip_runtime.h>
#include <math.h>

#define T_DIM 2048
#define B_DIM 4
#define BT (B_DIM * T_DIM)
#define MODEL 512
#define OUTF 256
#define WSZ 16
#define WIN 33

#define BM 128
#define BN 64
#define BK 32

#define TB 16    // t-rows per attn block (2 rows per wave, 8 waves)
#define HALO 48  // staged window rows (TB + 32)
#define TS 72    // padded k-stride for EwT/Ab (144B = 16B-aligned)

// 2*log2(e): GEMM epilogues store E = 2^(ESCALE*z) so attn needs no exp.
#define ESCALE 2.885390081777927f
#define ECLAMP 30.0f

typedef __attribute__((ext_vector_type(8))) short bf16x8;
typedef __attribute__((ext_vector_type(4))) float f32x4;

__device__ inline unsigned short f2bf(float f) {
  unsigned int u = __float_as_uint(f);
  u += 0x7fffu + ((u >> 16) & 1u);  // RNE
  return (unsigned short)(u >> 16);
}
__device__ inline float bflo(unsigned int u) {
  return __uint_as_float(u << 16);
}
__device__ inline float bfhi(unsigned int u) {
  return __uint_as_float(u & 0xffff0000u);
}
__device__ inline float fast_sigmoid(float z) {
  return __builtin_amdgcn_rcpf(1.f + __expf(-z));
}

// ---- m97-style GEMM body: BM=128 x BN=64 x BK=32, 8 waves, dbuf LDS,
// 2-deep register prefetch; B staged directly from f32 W via transpose-
// scatter. R19: the scatter was a ~32-way bank conflict (byte stride 320,
// brow pairs sharing dwords) — same class as R18's attn fix. XOR the
// k-granule by the col key on write AND read: k ^ (((col>>3)&3)<<3).
// MODE 0 (k rows [0,512)):  cb<4: x@Wh -> E-domain bf16 (+b_attn);
//                           cb>=4: x@Wl1 -> z1 f32 (+b_lin).
// MODE 1 (k rows [512,768)): cb<4: enc@We -> E-domain bf16;
//                            cb>=4: enc@Wl2 -> plain bf16.
template <int KS, int MODE>
__device__ __forceinline__ void gemm_body(
    unsigned short (*As)[BM * 40], unsigned short (*Bs)[BN * 40], int rb,
    const float* __restrict__ A, int lda,
    const float* __restrict__ W_attn, const float* __restrict__ W_lin,
    const float* __restrict__ b_attn, const float* __restrict__ b_lin,
    unsigned short* __restrict__ outb, float* __restrict__ outf,
    unsigned short* __restrict__ outb2) {
  const int tid = threadIdx.x;
  const int cb = rb >> 6, rp = rb & 63;  // bid%8 == rp%8 -> A panel per-XCD
  const int row0 = rp * BM;
  const int colg = (cb & 3) * 64;
  const float* Wsrc = (cb < 4) ? W_attn : W_lin;
  constexpr int wrow0 = (MODE == 0) ? 0 : 512;

  const int arow = tid >> 2, akp = (tid & 3) * 8;
  const int brow = tid >> 4, bcp = (tid & 15) * 4;
  const int bkey = (bcp >> 3) & 3;  // cols bcp..bcp+3 share one 8-block
  const float* aptr = A + (size_t)(row0 + arow) * lda + akp;
  const float* bptr = Wsrc + (size_t)(wrow0 + brow) * OUTF + colg + bcp;

  float4 ra0[2], ra1[2], rbw[2];
  auto LOADS = [&](int sl, int ks) {
    const float* ap = aptr + ks * BK;
    ra0[sl] = *(const float4*)ap;
    ra1[sl] = *(const float4*)(ap + 4);
    rbw[sl] = *(const float4*)(bptr + (size_t)ks * BK * OUTF);
  };
  auto WRITE = [&](int sl, int buf) {
    unsigned short t[8] = {f2bf(ra0[sl].x), f2bf(ra0[sl].y), f2bf(ra0[sl].z),
                           f2bf(ra0[sl].w), f2bf(ra1[sl].x), f2bf(ra1[sl].y),
                           f2bf(ra1[sl].z), f2bf(ra1[sl].w)};
    *(uint4*)&As[buf][arow * 40 + akp] = *(const uint4*)t;
    const int bk = brow ^ (bkey << 3);  // swizzled k position
    Bs[buf][(bcp + 0) * 40 + bk] = f2bf(rbw[sl].x);
    Bs[buf][(bcp + 1) * 40 + bk] = f2bf(rbw[sl].y);
    Bs[buf][(bcp + 2) * 40 + bk] = f2bf(rbw[sl].z);
    Bs[buf][(bcp + 3) * 40 + bk] = f2bf(rbw[sl].w);
  };

  const int w = tid >> 6, lane = tid & 63;
  const int lr = lane & 15, kg = lane >> 4;
  const int rbase = (w & 3) * 32;
  const int cbase = (w >> 2) * 32;
  // swizzled read offsets for the two B cols this lane touches
  const int bc0 = cbase + lr, bc1 = cbase + 16 + lr;
  const int bo0 = bc0 * 40 + ((kg ^ ((bc0 >> 3) & 3)) << 3);
  const int bo1 = bc1 * 40 + ((kg ^ ((bc1 >> 3) & 3)) << 3);

  f32x4 acc[2][2] = {{{0.f, 0.f, 0.f, 0.f}, {0.f, 0.f, 0.f, 0.f}},
                     {{0.f, 0.f, 0.f, 0.f}, {0.f, 0.f, 0.f, 0.f}}};

  LOADS(0, 0);
  if (KS > 1) LOADS(1, 1);
  WRITE(0, 0);
  __syncthreads();

#pragma unroll
  for (int ks = 0; ks < KS; ++ks) {
    if (ks + 2 < KS) LOADS(ks & 1, ks + 2);
    const int bf = ks & 1;
    bf16x8 a0 = *(const bf16x8*)&As[bf][(rbase + lr) * 40 + kg * 8];
    bf16x8 a1 = *(const bf16x8*)&As[bf][(rbase + 16 + lr) * 40 + kg * 8];
    bf16x8 b0 = *(const bf16x8*)&Bs[bf][bo0];
    bf16x8 b1 = *(const bf16x8*)&Bs[bf][bo1];
    acc[0][0] = __builtin_amdgcn_mfma_f32_16x16x32_bf16(a0, b0, acc[0][0], 0, 0, 0);
    acc[0][1] = __builtin_amdgcn_mfma_f32_16x16x32_bf16(a0, b1, acc[0][1], 0, 0, 0);
    acc[1][0] = __builtin_amdgcn_mfma_f32_16x16x32_bf16(a1, b0, acc[1][0], 0, 0, 0);
    acc[1][1] = __builtin_amdgcn_mfma_f32_16x16x32_bf16(a1, b1, acc[1][1], 0, 0, 0);
    if (ks + 1 < KS) WRITE((ks + 1) & 1, (ks + 1) & 1);
    __syncthreads();
  }

  // C/D layout: col=lane&15, row=(lane>>4)*4+r  [m89-verified]
#pragma unroll
  for (int m = 0; m < 2; ++m) {
#pragma unroll
    for (int f = 0; f < 2; ++f) {
      const int col = colg + cbase + f * 16 + lr;
#pragma unroll
      for (int r = 0; r < 4; ++r) {
        const int row = row0 + rbase + m * 16 + kg * 4 + r;
        float val = acc[m][f][r];
        if (MODE == 0) {
          if (cb < 4) {
            const float y = fminf((val + b_attn[col]) * ESCALE, ECLAMP);
            outb[(size_t)row * OUTF + col] = f2bf(__builtin_amdgcn_exp2f(y));
          } else {
            outf[(size_t)row * OUTF + col] = val + b_lin[col];
          }
        } else {
          if (cb < 4) {
            const float y = fminf(val * ESCALE, ECLAMP);
            outb[(size_t)row * OUTF + col] = f2bf(__builtin_amdgcn_exp2f(y));
          } else {
            outb2[(size_t)row * OUTF + col] = f2bf(val);
          }
        }
      }
    }
  }
}

// [0,512): x@[Wh|Wl1] -> xwe2,z1 ; [512,1024): enc@We -> ewe2, enc@Wl2 -> encWl2
__global__ __launch_bounds__(512) void gemmAB_kernel(
    const float* __restrict__ x, const float* __restrict__ enc,
    const float* __restrict__ W_attn, const float* __restrict__ W_lin,
    const float* __restrict__ b_attn, const float* __restrict__ b_lin,
    unsigned short* __restrict__ xwe2, float* __restrict__ z1,
    unsigned short* __restrict__ ewe2, unsigned short* __restrict__ encWl2) {
  __shared__ unsigned short As[2][BM * 40];
  __shared__ unsigned short Bs[2][BN * 40];
  if (blockIdx.x < 512)
    gemm_body<16, 0>(As, Bs, blockIdx.x, x, MODEL, W_attn, W_lin, b_attn,
                     b_lin, xwe2, z1, nullptr);
  else
    gemm_body<8, 1>(As, Bs, blockIdx.x - 512, enc, OUTF, W_attn, W_lin,
                    nullptr, nullptr, ewe2, nullptr, encWl2);
}

// ---- fused attention + banded final GEMM: 16 t-rows/block, 2 rows/wave ----
// G4 XOR swizzles on Ew (row-keyed) and EwT (col-keyed k-granule), write and
// read sides matched (R18, verified −6.3us).
__global__ __launch_bounds__(512) void attn_gemmc_kernel(
    const unsigned short* __restrict__ xwe2,
    const unsigned short* __restrict__ ewe2,
    const unsigned short* __restrict__ encWl2, const float* __restrict__ v,
    const float* __restrict__ z1, float* __restrict__ out,
    float* __restrict__ a_out) {
  __shared__ unsigned short Ew[HALO * 256];  // 2^encwe halo (24.6 KB)
  __shared__ unsigned short EwT[256 * TS];   // (encWl2 halo)^T (36.9 KB)
  __shared__ unsigned short Ab[TB * TS];     // banded a (2.3 KB)

  const int tid = threadIdx.x;
  const int wv = tid >> 6, lane = tid & 63;
  const int rb = ((blockIdx.x & 7) << 6) | (blockIdx.x >> 3);  // XCD-grouped
  const int t0 = rb * TB;
  const int b = t0 >> 11;
  const int tloc = t0 & (T_DIM - 1);
  const int g = lane >> 4, sl = lane & 15;

  // zero Ab (cols >=48 must be 0 for the K=64 MFMA)
  if (tid < TB * TS / 8) ((uint4*)Ab)[tid] = make_uint4(0, 0, 0, 0);
  // zero EwT k-granules that staging doesn't cover (swizzled positions)
  {
    const int col = tid >> 1, off = 48 + (tid & 1) * 8;
    const int kswz = ((col >> 3) & 7) << 3;
    *(uint4*)&EwT[col * TS + (off ^ kswz)] = make_uint4(0, 0, 0, 0);
  }

  // stage Ew (2^ewe, OOB rows = 1.0) and EwT (encWl2 transposed, OOB = 0)
  for (int u = tid; u < HALO * 32; u += 512) {
    const int r = u >> 5, s = u & 31;
    const int tg = tloc - WSZ + r;
    uint4 qe, qw;
    if ((unsigned)tg < T_DIM) {
      const size_t base = ((size_t)(b * T_DIM + tg)) << 8;
      qe = *(const uint4*)(ewe2 + base + s * 8);
      qw = *(const uint4*)(encWl2 + base + s * 8);
    } else {
      qe = make_uint4(0x3f803f80u, 0x3f803f80u, 0x3f803f80u, 0x3f803f80u);
      qw = make_uint4(0, 0, 0, 0);
    }
    *(uint4*)&Ew[(r * 256 + s * 8) ^ ((r & 7) << 3)] = qe;
    unsigned short tt[8];
    *(uint4*)tt = qw;
    const int rsw = r ^ ((s & 7) << 3);  // key = col>>3 = s
#pragma unroll
    for (int j = 0; j < 8; ++j) EwT[(s * 8 + j) * TS + rsw] = tt[j];
  }

  float vf[16];
  {
    const float4* vp = (const float4*)(v + sl * 16);
#pragma unroll
    for (int j = 0; j < 4; ++j) {
      float4 t4 = vp[j];
      vf[4 * j] = t4.x; vf[4 * j + 1] = t4.y;
      vf[4 * j + 2] = t4.z; vf[4 * j + 3] = t4.w;
    }
  }
  __syncthreads();

  const int lrow = wv * 2;
  const int bt0 = t0 + lrow, bt1 = bt0 + 1;

  float xe0[16], xe1[16];
  {
    const uint4* xp0 = (const uint4*)(xwe2 + ((size_t)bt0 << 8) + sl * 16);
    const uint4* xp1 = (const uint4*)(xwe2 + ((size_t)bt1 << 8) + sl * 16);
    uint4 q0 = xp0[0], q1 = xp0[1], q2 = xp1[0], q3 = xp1[1];
    unsigned int u0[8] = {q0.x, q0.y, q0.z, q0.w, q1.x, q1.y, q1.z, q1.w};
    unsigned int u1[8] = {q2.x, q2.y, q2.z, q2.w, q3.x, q3.y, q3.z, q3.w};
#pragma unroll
    for (int j = 0; j < 8; ++j) {
      xe0[2 * j] = bflo(u0[j]); xe0[2 * j + 1] = bfhi(u0[j]);
      xe1[2 * j] = bflo(u1[j]); xe1[2 * j + 1] = bfhi(u1[j]);
    }
  }

  // scores for BOTH rows: 9 chunks x 4 windows (16 lanes each)
  float s0 = 0.f, s1 = 0.f;
#pragma unroll
  for (int c = 0; c < 9; ++c) {
    const int w_ = c * 4 + g;
    const int rl0 = min(lrow + w_, HALO - 1);
    const int rl1 = min(lrow + 1 + w_, HALO - 1);
    const int x0 = (rl0 & 7) << 3, x1 = (rl1 & 7) << 3;
    const int b0i = rl0 * 256 + sl * 16, b1i = rl1 * 256 + sl * 16;
    const uint4 a0q = *(const uint4*)&Ew[b0i ^ x0];
    const uint4 a1q = *(const uint4*)&Ew[(b0i + 8) ^ x0];
    const uint4 b0q = *(const uint4*)&Ew[b1i ^ x1];
    const uint4 b1q = *(const uint4*)&Ew[(b1i + 8) ^ x1];
    unsigned int e0[8] = {a0q.x, a0q.y, a0q.z, a0q.w, a1q.x, a1q.y, a1q.z, a1q.w};
    unsigned int e1[8] = {b0q.x, b0q.y, b0q.z, b0q.w, b1q.x, b1q.y, b1q.z, b1q.w};
    float acc0 = 0.f, acc1 = 0.f;
#pragma unroll
    for (int j = 0; j < 8; ++j) {
      const float v0 = vf[2 * j], v1 = vf[2 * j + 1];
      const float vsj = v0 + v1;
      {
        const float E0 = xe0[2 * j] * bflo(e0[j]);
        const float E1 = xe0[2 * j + 1] * bfhi(e0[j]);
        const float den = (E0 + 1.f) * (E1 + 1.f);
        float num = fmaf(v0, E1, vsj);
        num = fmaf(v1, E0, num);
        acc0 = fmaf(num, __builtin_amdgcn_rcpf(den), acc0);
      }
      {
        const float E0 = xe1[2 * j] * bflo(e1[j]);
        const float E1 = xe1[2 * j + 1] * bfhi(e1[j]);
        const float den = (E0 + 1.f) * (E1 + 1.f);
        float num = fmaf(v0, E1, vsj);
        num = fmaf(v1, E0, num);
        acc1 = fmaf(num, __builtin_amdgcn_rcpf(den), acc1);
      }
    }
#pragma unroll
    for (int off = 1; off < 16; off <<= 1) {
      acc0 += __shfl_xor(acc0, off);
      acc1 += __shfl_xor(acc1, off);
    }
    const int src = (lane & 3) << 4;
    float c0v = __shfl(acc0, src), c1v = __shfl(acc1, src);
    if ((lane >> 2) == c) { s0 = c0v; s1 = c1v; }
  }

  // softmax without max-subtraction: score=-2S, |S|<=sum|v|~4.2 -> safe
  float p0 = (lane < WIN) ? __builtin_amdgcn_exp2f(-ESCALE * s0) : 0.f;
  float p1 = (lane < WIN) ? __builtin_amdgcn_exp2f(-ESCALE * s1) : 0.f;
  float q0 = p0, q1 = p1;
#pragma unroll
  for (int off = 1; off < 64; off <<= 1) {
    q0 += __shfl_xor(q0, off);
    q1 += __shfl_xor(q1, off);
  }
  const float a0v = p0 * __builtin_amdgcn_rcpf(q0);
  const float a1v = p1 * __builtin_amdgcn_rcpf(q1);
  if (lane < WIN) {
    a_out[(size_t)bt0 * WIN + lane] = a0v;
    a_out[(size_t)bt1 * WIN + lane] = a1v;
    // banded a-matrix: Ab[t][t+w] = a[t][w]; rest stays 0.
    Ab[lrow * TS + lrow + lane] = f2bf(a0v);
    Ab[(lrow + 1) * TS + (lrow + 1) + lane] = f2bf(a1v);
  }
  __syncthreads();

  // banded GEMM: out[16,256] = sigmoid(z1 + Ab(16x64) @ EwT^T(64x256))
  const int lr = lane & 15, kg = lane >> 4;
  f32x4 acc[2] = {{0.f, 0.f, 0.f, 0.f}, {0.f, 0.f, 0.f, 0.f}};
#pragma unroll
  for (int ks = 0; ks < 2; ++ks) {
    bf16x8 a = *(const bf16x8*)&Ab[lr * TS + ks * 32 + kg * 8];
#pragma unroll
    for (int f = 0; f < 2; ++f) {
      const int colB = wv * 32 + f * 16 + lr;
      const int kswz = ((colB >> 3) & 7) << 3;
      bf16x8 bb = *(const bf16x8*)&EwT[colB * TS + ((ks * 32 + kg * 8) ^ kswz)];
      acc[f] = __builtin_amdgcn_mfma_f32_16x16x32_bf16(a, bb, acc[f], 0, 0, 0);
    }
  }
#pragma unroll
  for (int f = 0; f < 2; ++f) {
    const int col = wv * 32 + f * 16 + lr;
#pragma unroll
    for (int r = 0; r < 4; ++r) {
      const int row = t0 + kg * 4 + r;
      out[(size_t)row * OUTF + col] =
          fast_sigmoid(acc[f][r] + z1[(size_t)row * OUTF + col]);
    }
  }
}

extern "C" void kernel_launch(void* const* d_in, const int* in_sizes, int n_in,
                              void* d_out, int out_size, void* d_ws,
                              size_t ws_size, hipStream_t stream) {
  const float* x      = (const float*)d_in[0];  // [4,2048,512]
  const float* enc    = (const float*)d_in[1];  // [4,2048,256]
  const float* W_attn = (const float*)d_in[2];  // [768,256]
  const float* b_attn = (const float*)d_in[3];  // [256]
  const float* v      = (const float*)d_in[4];  // [256]
  const float* W_lin  = (const float*)d_in[5];  // [768,256]
  const float* b_lin  = (const float*)d_in[6];  // [256]

  float* out   = (float*)d_out;            // [BT,256]
  float* a_out = out + (size_t)BT * OUTF;  // [BT,33]

  unsigned short* xwe2   = (unsigned short*)d_ws;     // BT*256 bf16 (2^ vals)
  unsigned short* ewe2   = xwe2 + (size_t)BT * OUTF;  // BT*256 bf16 (2^ vals)
  unsigned short* encWl2 = ewe2 + (size_t)BT * OUTF;  // BT*256 bf16
  float*          z1     = (float*)(encWl2 + (size_t)BT * OUTF);  // BT*256 f32

  // x@[Wh|Wl1] -> xwe2,z1 ; enc@We -> ewe2 ; enc@Wl2 -> encWl2
  gemmAB_kernel<<<1024, 512, 0, stream>>>(x, enc, W_attn, W_lin, b_attn,
                                          b_lin, xwe2, z1, ewe2, encWl2);
  // fused attention + banded final GEMM (+sigmoid) -> out, a_out
  attn_gemmc_kernel<<<512, 512, 0, stream>>>(xwe2, ewe2, encWl2, v, z1,
                                             out, a_out);
}